// Round 1
// baseline (157.605 us; speedup 1.0000x reference)
//
#include <hip/hip_runtime.h>
#include <math.h>

#define N 8
#define C 256
#define L 512
#define K 100
#define NL (N * L)
#define TEMP_INV 2.0f
#define EPSN 1e-8f

// ws layout (floats): zt[NL*C] | ct[NL*C] | zinv[NL] | cinv[NL]  -> ~8.4 MB

// Kernel 1: LDS-tiled transpose (N,C,L)->(NL,C) for z and c (dropping c's start
// token), plus per-column sum-of-squares -> inverse norms. Also zeroes d_out.
__global__ __launch_bounds__(256) void prep_kernel(
    const float* __restrict__ z, const float* __restrict__ c,
    float* __restrict__ zt, float* __restrict__ ct,
    float* __restrict__ zinv, float* __restrict__ cinv,
    float* __restrict__ out)
{
    if (blockIdx.x == 0 && threadIdx.x == 0) out[0] = 0.f;

    __shared__ float lds[64 * 65];   // 64c x 64l tile, pad 65 to kill conflicts
    __shared__ float red[256];

    const int b = blockIdx.x;
    const int is_c = b >= (N * (L / 64));          // first 64 blocks: z, next 64: c
    const int bb = is_c ? b - N * (L / 64) : b;
    const int n  = bb >> 3;                        // L/64 = 8 tiles per n
    const int l0 = (bb & 7) << 6;
    const int ld = is_c ? (L + 1) : L;
    const float* src = is_c ? (c + (size_t)n * C * (L + 1) + l0 + 1)
                            : (z + (size_t)n * C * L + l0);
    float* dst = (is_c ? ct : zt) + (size_t)(n * L + l0) * C;
    float* inv = (is_c ? cinv : zinv) + n * L + l0;

    const int t  = threadIdx.x;
    const int tx = t & 63;     // local l (load) / local c (store)
    const int ty = t >> 6;

    float ss = 0.f;            // sum of squares for column l0+tx
    for (int cc = 0; cc < 4; ++cc) {
        for (int i = 0; i < 16; ++i) {
            int cl = i * 4 + ty;                       // local c within tile
            float v = src[(size_t)(cc * 64 + cl) * ld + tx];   // coalesced in tx
            lds[cl * 65 + tx] = v;
            ss += v * v;
        }
        __syncthreads();
        for (int i = 0; i < 16; ++i) {
            int ll = i * 4 + ty;                       // local l
            dst[(size_t)ll * C + cc * 64 + tx] = lds[tx * 65 + ll];  // coalesced in tx
        }
        __syncthreads();
    }
    red[t] = ss;
    __syncthreads();
    if (ty == 0) {
        float tot = red[tx] + red[64 + tx] + red[128 + tx] + red[192 + tx];
        inv[tx] = 1.f / fmaxf(sqrtf(tot), EPSN);
    }
}

// Kernel 2: one wave per (n,l) row. Registers hold the raw cn fragment
// (float4/lane). 101 coalesced gathered dots, butterfly reduce, online LSE.
__global__ __launch_bounds__(256) void logits_kernel(
    const float* __restrict__ zt, const float* __restrict__ ct,
    const float* __restrict__ zinv, const float* __restrict__ cinv,
    const int* __restrict__ neg, float* __restrict__ out)
{
    const int w    = threadIdx.x >> 6;
    const int lane = threadIdx.x & 63;
    const int row  = blockIdx.x * 4 + w;

    const float4 cf = *(const float4*)(ct + (size_t)row * C + lane * 4);
    const float  ci = cinv[row];

    // positive logit
    {
    }
    const float4 zf = *(const float4*)(zt + (size_t)row * C + lane * 4);
    float d = cf.x * zf.x + cf.y * zf.y + cf.z * zf.z + cf.w * zf.w;
    #pragma unroll
    for (int m = 1; m < 64; m <<= 1) d += __shfl_xor(d, m, 64);
    const float pos = d * ci * zinv[row] * TEMP_INV;   // already /TEMP

    float mx = pos, s = 1.f;                           // online logsumexp state
    const int* __restrict__ np_ = neg + (size_t)row * K;

    for (int k = 0; k < K; k += 2) {
        const int i0 = np_[k];
        const int i1 = np_[k + 1];
        const float4 n0 = *(const float4*)(zt + (size_t)i0 * C + lane * 4);
        const float4 n1 = *(const float4*)(zt + (size_t)i1 * C + lane * 4);
        const float zi0 = zinv[i0];
        const float zi1 = zinv[i1];
        float d0 = cf.x * n0.x + cf.y * n0.y + cf.z * n0.z + cf.w * n0.w;
        float d1 = cf.x * n1.x + cf.y * n1.y + cf.z * n1.z + cf.w * n1.w;
        #pragma unroll
        for (int m = 1; m < 64; m <<= 1) {
            d0 += __shfl_xor(d0, m, 64);
            d1 += __shfl_xor(d1, m, 64);
        }
        const float sim0 = d0 * ci * zi0;
        const float sim1 = d1 * ci * zi1;

        bool skip0 = false, skip1 = false;
        if (sim0 > 0.99999f) {   // only exact-equal vectors can hit cos==1
            int eq = (cf.x == n0.x) & (cf.y == n0.y) & (cf.z == n0.z) & (cf.w == n0.w);
            skip0 = __all(eq);   // masked -inf: contributes 0 to sumexp
        }
        if (sim1 > 0.99999f) {
            int eq = (cf.x == n1.x) & (cf.y == n1.y) & (cf.z == n1.z) & (cf.w == n1.w);
            skip1 = __all(eq);
        }
        if (!skip0) {
            float x  = sim0 * TEMP_INV;
            float mn = fmaxf(mx, x);
            s  = s * __expf(mx - mn) + __expf(x - mn);
            mx = mn;
        }
        if (!skip1) {
            float x  = sim1 * TEMP_INV;
            float mn = fmaxf(mx, x);
            s  = s * __expf(mx - mn) + __expf(x - mn);
            mx = mn;
        }
    }

    const float lse = mx + __logf(s);
    if (lane == 0) atomicAdd(out, (lse - pos) * (1.0f / NL));
}

extern "C" void kernel_launch(void* const* d_in, const int* in_sizes, int n_in,
                              void* d_out, int out_size, void* d_ws, size_t ws_size,
                              hipStream_t stream) {
    const float* z  = (const float*)d_in[0];
    const float* c  = (const float*)d_in[1];
    const int* neg  = (const int*)d_in[2];
    float* out = (float*)d_out;

    float* zt   = (float*)d_ws;
    float* ct   = zt + (size_t)NL * C;
    float* zinv = ct + (size_t)NL * C;
    float* cinv = zinv + NL;

    prep_kernel<<<2 * N * (L / 64), 256, 0, stream>>>(z, c, zt, ct, zinv, cinv, out);
    logits_kernel<<<NL / 4, 256, 0, stream>>>(zt, ct, zinv, cinv, neg, out);
}